// Round 1
// baseline (190.511 us; speedup 1.0000x reference)
//
#include <hip/hip_runtime.h>

typedef unsigned short u16;
typedef unsigned int u32;
typedef __bf16 bf16x8 __attribute__((ext_vector_type(8)));
typedef float f32x4 __attribute__((ext_vector_type(4)));

__device__ __forceinline__ u16 f2bf(float f) {
  u32 u = __builtin_bit_cast(u32, f);
  u = (u + 0x7FFFu + ((u >> 16) & 1u)) >> 16;
  return (u16)u;
}
__device__ __forceinline__ float bf2f(u16 h) {
  u32 u = ((u32)h) << 16;
  return __builtin_bit_cast(float, u);
}

#define GLD16(gp, lp) __builtin_amdgcn_global_load_lds( \
    (const __attribute__((address_space(1))) u32*)(const void*)(gp), \
    (__attribute__((address_space(3))) u32*)(void*)(lp), 16, 0, 0)

// ---------------------------------------------------------------------------
// fp32 -> bf16 cast (weights)
__global__ __launch_bounds__(256) void cast_f32_bf16(const float* __restrict__ src,
                                                     u16* __restrict__ dst, int n4) {
  int i = blockIdx.x * 256 + threadIdx.x;
  if (i < n4) {
    float4 v = *(const float4*)(src + (size_t)i * 4);
    ushort4 u;
    u.x = f2bf(v.x); u.y = f2bf(v.y); u.z = f2bf(v.z); u.w = f2bf(v.w);
    *(ushort4*)(dst + (size_t)i * 4) = u;
  }
}

// ---------------------------------------------------------------------------
// permute_in: x (B,C,64,64,64) fp32, roll(+4) + window partition -> xw (B*4096, 512) bf16
// xw[b, n=(jx,jy,jz), e=(c,qx,qy,qz)] = x[b,c,(jx*4+qx+60)%64,(jy*4+qy+60)%64,(jz*4+qz+60)%64]
__global__ __launch_bounds__(256) void permute_in(const float* __restrict__ x,
                                                  u16* __restrict__ xw) {
  __shared__ float lds[128 * 64];  // [row=(c,qx,qy)][Z], quad-swizzled
  int t = threadIdx.x;
  int bx = blockIdx.x;                 // jx*16 + jy
  int b = blockIdx.y;
  int jx = bx >> 4, jy = bx & 15;
#pragma unroll
  for (int it = 0; it < 8; ++it) {
    int idx = t + it * 256;            // 2048 float4 quads
    int row = idx >> 4, z4 = idx & 15;
    int c = row >> 4, qx = (row >> 2) & 3, qy = row & 3;
    int X = (jx * 4 + qx + 60) & 63;
    int Y = (jy * 4 + qy + 60) & 63;
    float4 v = *(const float4*)(x + ((((size_t)(b * 8 + c) * 64 + X) * 64 + Y) * 64 + z4 * 4));
    *(float4*)(lds + row * 64 + ((z4 ^ (row & 7)) << 2)) = v;
  }
  __syncthreads();
#pragma unroll
  for (int it = 0; it < 8; ++it) {
    int idx = t + it * 256;
    int jz = idx >> 7, r = idx & 127;  // r = c*16+qx*4+qy, e = r*4 + qz
    int z4r = (jz + 15) & 15;          // ((jz*4+60)%64)/4
    float4 v = *(const float4*)(lds + r * 64 + ((z4r ^ (r & 7)) << 2));
    int nw = jx * 256 + jy * 16 + jz;
    ushort4 u;
    u.x = f2bf(v.x); u.y = f2bf(v.y); u.z = f2bf(v.z); u.w = f2bf(v.w);
    *(ushort4*)(xw + (size_t)(b * 4096 + nw) * 512 + r * 4) = u;
  }
}

// ---------------------------------------------------------------------------
// GEMM: C[M,N] = A[M,K] @ W[N,K]^T + bias, all bf16 except bias/acc fp32.
// m97-style: 128x128 tile, BK=32, 4 waves (2x2), 16x16x32 MFMA, global_load_lds w16.
__global__ __launch_bounds__(256) void gemm_bt(const u16* __restrict__ A,
                                               const u16* __restrict__ W,
                                               const float* __restrict__ bias,
                                               u16* __restrict__ C,
                                               int M, int N, int K) {
  __shared__ u16 As[128 * 32];
  __shared__ u16 Bs[128 * 32];
  int t = threadIdx.x;
  int w = t >> 6, l = t & 63;
  int m0 = blockIdx.y * 128;
  int n0 = blockIdx.x * 128;
  int wr = w >> 1, wc = w & 1;
  int lr = l & 15, lg = l >> 4;

  f32x4 acc[4][4] = {};

  for (int k0 = 0; k0 < K; k0 += 32) {
#pragma unroll
    for (int i = 0; i < 2; ++i) {
      int cbase = w * 128 + i * 64;
      int c = cbase + l;
      int row = c >> 2, k8 = (c & 3) * 8;
      GLD16(A + (size_t)(m0 + row) * K + k0 + k8, As + cbase * 8);
      GLD16(W + (size_t)(n0 + row) * K + k0 + k8, Bs + cbase * 8);
    }
    __syncthreads();
    bf16x8 a[4], b[4];
#pragma unroll
    for (int m = 0; m < 4; ++m)
      a[m] = *(const bf16x8*)(As + (wr * 64 + m * 16 + lr) * 32 + lg * 8);
#pragma unroll
    for (int n = 0; n < 4; ++n)
      b[n] = *(const bf16x8*)(Bs + (wc * 64 + n * 16 + lr) * 32 + lg * 8);
#pragma unroll
    for (int m = 0; m < 4; ++m)
#pragma unroll
      for (int n = 0; n < 4; ++n)
        acc[m][n] = __builtin_amdgcn_mfma_f32_16x16x32_bf16(a[m], b[n], acc[m][n], 0, 0, 0);
    __syncthreads();
  }

#pragma unroll
  for (int n = 0; n < 4; ++n) {
    int col = n0 + wc * 64 + n * 16 + lr;
    float bv = bias[col];
#pragma unroll
    for (int m = 0; m < 4; ++m) {
      int rowb = m0 + wr * 64 + m * 16 + lg * 4;
#pragma unroll
      for (int j = 0; j < 4; ++j)
        C[(size_t)(rowb + j) * N + col] = f2bf(acc[m][n][j] + bv);
    }
  }
}

// ---------------------------------------------------------------------------
// attention: per (n,h) unit, q,k,v are (8 x 64). One wave per unit.
// lane = (i=l>>3, j=l&7): S[i][j] -> softmax over j-group -> o[i][j*8..j*8+8)
__global__ __launch_bounds__(256) void attn(const u16* __restrict__ qkv,
                                            u16* __restrict__ o) {
  __shared__ float lds[4][3][8][68];
  int widx = threadIdx.x >> 6, l = threadIdx.x & 63;
  int unit = blockIdx.x * 4 + widx;
  int n = unit >> 3, h = unit & 7;

  int i = l >> 3, seg = l & 7;
  const u16* base = qkv + (size_t)(i * 4096 + n) * 1536 + h * 64 + seg * 8;
#pragma unroll
  for (int tt = 0; tt < 3; ++tt) {
    ushort4 u0 = *(const ushort4*)(base + tt * 512);
    ushort4 u1 = *(const ushort4*)(base + tt * 512 + 4);
    float* dst = &lds[widx][tt][i][seg * 8];
    float4 f0, f1;
    f0.x = bf2f(u0.x); f0.y = bf2f(u0.y); f0.z = bf2f(u0.z); f0.w = bf2f(u0.w);
    f1.x = bf2f(u1.x); f1.y = bf2f(u1.y); f1.z = bf2f(u1.z); f1.w = bf2f(u1.w);
    *(float4*)dst = f0;
    *(float4*)(dst + 4) = f1;
  }
  __syncthreads();

  int j = l & 7;
  const float* q = &lds[widx][0][i][0];
  const float* k = &lds[widx][1][j][0];
  float s = 0.f;
#pragma unroll
  for (int d = 0; d < 64; d += 4) {
    float4 qv = *(const float4*)(q + d);
    float4 kv = *(const float4*)(k + d);
    s += qv.x * kv.x + qv.y * kv.y + qv.z * kv.z + qv.w * kv.w;
  }
  s *= 0.125f;
  float mx = s;
  mx = fmaxf(mx, __shfl_xor(mx, 1));
  mx = fmaxf(mx, __shfl_xor(mx, 2));
  mx = fmaxf(mx, __shfl_xor(mx, 4));
  float p = __expf(s - mx);
  float sum = p;
  sum += __shfl_xor(sum, 1);
  sum += __shfl_xor(sum, 2);
  sum += __shfl_xor(sum, 4);
  p = p / sum;

  float pr[8];
  int lbase = l & 56;
#pragma unroll
  for (int jj = 0; jj < 8; ++jj) pr[jj] = __shfl(p, lbase + jj);

  float oa[8] = {0, 0, 0, 0, 0, 0, 0, 0};
#pragma unroll
  for (int jj = 0; jj < 8; ++jj) {
    const float* v = &lds[widx][2][jj][j * 8];
    float4 va = *(const float4*)(v);
    float4 vb = *(const float4*)(v + 4);
    oa[0] += pr[jj] * va.x; oa[1] += pr[jj] * va.y;
    oa[2] += pr[jj] * va.z; oa[3] += pr[jj] * va.w;
    oa[4] += pr[jj] * vb.x; oa[5] += pr[jj] * vb.y;
    oa[6] += pr[jj] * vb.z; oa[7] += pr[jj] * vb.w;
  }
  u16* dst = o + (size_t)(i * 4096 + n) * 512 + h * 64 + j * 8;
  ushort4 r0, r1;
  r0.x = f2bf(oa[0]); r0.y = f2bf(oa[1]); r0.z = f2bf(oa[2]); r0.w = f2bf(oa[3]);
  r1.x = f2bf(oa[4]); r1.y = f2bf(oa[5]); r1.z = f2bf(oa[6]); r1.w = f2bf(oa[7]);
  *(ushort4*)dst = r0;
  *(ushort4*)(dst + 4) = r1;
}

// ---------------------------------------------------------------------------
// permute_out: o2 (B*4096, 512) bf16 -> out (B,C,64,64,64) fp32 (reassembly + roll(-4))
// out[b,c,u,v,w] = o2[b, n=(ix,iy,iz), f=(c,px,py,pz)], U=(u+4)%64=px*16+ix etc.
__global__ __launch_bounds__(256) void permute_out(const u16* __restrict__ o2,
                                                   float* __restrict__ out) {
  __shared__ float lds[16 * 516];  // [iz][f], padded
  int t = threadIdx.x;
  int bx = blockIdx.x;             // ix*16+iy
  int b = blockIdx.y;
  int ix = bx >> 4, iy = bx & 15;
  int n0 = ix * 256 + iy * 16;
#pragma unroll
  for (int it = 0; it < 8; ++it) {
    int idx = t + it * 256;        // 2048 quads: 16 iz-rows x 128 f-quads
    int iz = idx >> 7, fq = idx & 127;
    ushort4 u = *(const ushort4*)(o2 + ((size_t)(b * 4096 + n0 + iz) * 512 + fq * 4));
    float4 v;
    v.x = bf2f(u.x); v.y = bf2f(u.y); v.z = bf2f(u.z); v.w = bf2f(u.w);
    *(float4*)(lds + iz * 516 + fq * 4) = v;
  }
  __syncthreads();
#pragma unroll
  for (int it = 0; it < 8; ++it) {
    int idx = t + it * 256;        // 2048 quads: 128 fidx x 16 w4
    int fidx = idx >> 4, w4 = idx & 15;
    int c = fidx >> 4, px = (fidx >> 2) & 3, py = fidx & 3;
    int W0 = (w4 * 4 + 4) & 63;
    int pz = W0 >> 4, iz0 = W0 & 15;
    int fa = fidx * 4 + pz;
    float4 v;
    v.x = lds[(iz0 + 0) * 516 + fa];
    v.y = lds[(iz0 + 1) * 516 + fa];
    v.z = lds[(iz0 + 2) * 516 + fa];
    v.w = lds[(iz0 + 3) * 516 + fa];
    int uu = (px * 16 + ix + 60) & 63;
    int vv = (py * 16 + iy + 60) & 63;
    *(float4*)(out + ((((size_t)(b * 8 + c) * 64 + uu) * 64 + vv) * 64 + w4 * 4)) = v;
  }
}

// ---------------------------------------------------------------------------
extern "C" void kernel_launch(void* const* d_in, const int* in_sizes, int n_in,
                              void* d_out, int out_size, void* d_ws, size_t ws_size,
                              hipStream_t stream) {
  const float* x     = (const float*)d_in[0];
  const float* w_in  = (const float*)d_in[1];
  const float* b_in  = (const float*)d_in[2];
  const float* w_out = (const float*)d_in[3];
  const float* b_out = (const float*)d_in[4];
  float* out = (float*)d_out;

  char* ws = (char*)d_ws;
  u16* wq  = (u16*)(ws);                      // 1536*512 bf16
  u16* wo  = (u16*)(ws + 1572864);            // 512*512 bf16
  u16* xw  = (u16*)(ws + 2097152);            // 32768*512 bf16 (reused as o)
  u16* qkv = (u16*)(ws + 35651584);           // 32768*1536 bf16
  u16* o2  = (u16*)(ws + 136314880);          // 32768*512 bf16
  // total ws use: 169,869,312 bytes

  cast_f32_bf16<<<768, 256, 0, stream>>>(w_in, wq, 196608);
  cast_f32_bf16<<<256, 256, 0, stream>>>(w_out, wo, 65536);
  permute_in<<<dim3(256, 8), 256, 0, stream>>>(x, xw);
  gemm_bt<<<dim3(12, 256), 256, 0, stream>>>(xw, wq, b_in, qkv, 32768, 1536, 512);
  attn<<<8192, 256, 0, stream>>>(qkv, xw);    // o aliases xw (xw dead after QKV gemm)
  gemm_bt<<<dim3(4, 256), 256, 0, stream>>>(xw, wo, b_out, o2, 32768, 512, 512);
  permute_out<<<dim3(256, 8), 256, 0, stream>>>(o2, out);
}